// Round 3
// baseline (244.446 us; speedup 1.0000x reference)
//
#include <hip/hip_runtime.h>
#include <cstdint>

typedef unsigned int u32;
typedef unsigned short u16;

#define N_NODES 100000
#define N_EDGES 3200000
#define F_IN 128
#define DIM 10
#define QB 16            // bf16 elems per padded q row -> 32B
#define HPAD 12          // f32 h2 row stride (48B) for the pool kernel
#define B_GRAPHS 1000
#define NBLK_N 391       // ceil(N/256) gemm blocks

// Single-level bucketing: 782 buckets of 128 dst nodes each (dst>>7).
// CHUNK_C=32768: per-(block,bucket) scatter segments ~42 records (~168B,
// ~2.6 lines) -> write amplification ~1.3x. (CHUNK_C=8192 gave 10.5-record
// segments: every line shared across XCDs -> 5x RMW blowup, 77MB WRITE_SIZE.)
#define SHIFTC 7
#define NBINS 128        // dst & 127 within a bucket
#define NCB 782          // ceil(N/128)
#define CAPC 4608        // slots/bucket: mean 4092 + 8 sigma
#define CHUNK_C 32768    // edges per bucketing block
#define NBLK_C 98        // ceil(E/CHUNK_C)
#define GSTRIDE 16       // cursor padding: one 64B line per cursor
#define SEGW 129         // segment-start words per bucket (NBINS+1)

__device__ __forceinline__ u16 f2b(float f) {           // f32 -> bf16 (RNE)
  union { float f; u32 i; } c; c.f = f;
  u32 r = c.i + 0x7FFFu + ((c.i >> 16) & 1u);
  return (u16)(r >> 16);
}
__device__ __forceinline__ float bl(u32 u) {            // low bf16 -> f32
  union { u32 i; float f; } c; c.i = u << 16; return c.f;
}
__device__ __forceinline__ float bh(u32 u) {            // high bf16 -> f32
  union { u32 i; float f; } c; c.i = u & 0xFFFF0000u; return c.f;
}

// ---- gemm1 body: 1 thread/node, wave-uniform W indexing (s_loads) ----
__device__ __forceinline__ void gemm_body(
    int bid, int tid,
    const float* __restrict__ x, const float* __restrict__ W,
    float* __restrict__ p1, u16* __restrict__ q1b)
{
  int i = bid * 256 + tid;
  if (i >= N_NODES) return;
  const float4* __restrict__ xr = (const float4*)(x + (size_t)i * F_IN);
  float ap[DIM], aq[DIM];
  #pragma unroll
  for (int j = 0; j < DIM; ++j) { ap[j] = 0.f; aq[j] = 0.f; }
  #pragma unroll 4
  for (int k4 = 0; k4 < F_IN / 4; ++k4) {
    float4 v = xr[k4];
    const float* __restrict__ w0 = W + (k4 * 4) * DIM;
    const float* __restrict__ w1 = W + (F_IN + k4 * 4) * DIM;
    #pragma unroll
    for (int j = 0; j < DIM; ++j) {
      ap[j] += v.x * w0[j] + v.y * w0[DIM + j] + v.z * w0[2 * DIM + j] + v.w * w0[3 * DIM + j];
      aq[j] += v.x * w1[j] + v.y * w1[DIM + j] + v.z * w1[2 * DIM + j] + v.w * w1[3 * DIM + j];
    }
  }
  float* pr = p1 + (size_t)i * DIM;
  #pragma unroll
  for (int j = 0; j < DIM; ++j) pr[j] = ap[j];
  u32* qr = (u32*)(q1b + (size_t)i * QB);
  uint4 v0; u32 v1;
  v0.x = (u32)f2b(aq[0]) | ((u32)f2b(aq[1]) << 16);
  v0.y = (u32)f2b(aq[2]) | ((u32)f2b(aq[3]) << 16);
  v0.z = (u32)f2b(aq[4]) | ((u32)f2b(aq[5]) << 16);
  v0.w = (u32)f2b(aq[6]) | ((u32)f2b(aq[7]) << 16);
  v1   = (u32)f2b(aq[8]) | ((u32)f2b(aq[9]) << 16);
  *(uint4*)qr = v0;
  qr[4] = v1;
}

// ---- bucketing body: partition edges into 782 ranges (128 dst each) ----
// Record: ((dst & 127) << 17) | src   (src < 2^17)
__device__ __forceinline__ void coarse_body(
    int bid, int tid,
    const int* __restrict__ src, const int* __restrict__ dst,
    u32* __restrict__ gcurc, u32* __restrict__ coarse)
{
  __shared__ u32 hcnt[NCB];
  __shared__ u32 gbase[NCB];
  for (int t = tid; t < NCB; t += 256) hcnt[t] = 0u;
  __syncthreads();
  int base = bid * CHUNK_C;
  const int4* __restrict__ dst4 = (const int4*)dst;
  const int4* __restrict__ src4 = (const int4*)src;
  // pass 1: histogram (int4 loads: 4 edges/thread/iter, 4 indep atomics)
  #pragma unroll 4
  for (int it = 0; it < CHUNK_C / 1024; ++it) {
    int e = base + it * 1024 + tid * 4;
    if (e < N_EDGES) {     // N_EDGES % 4 == 0, e % 4 == 0 -> whole int4 ok
      int4 d = dst4[(base >> 2) + it * 256 + tid];
      atomicAdd(&hcnt[(u32)d.x >> SHIFTC], 1u);
      atomicAdd(&hcnt[(u32)d.y >> SHIFTC], 1u);
      atomicAdd(&hcnt[(u32)d.z >> SHIFTC], 1u);
      atomicAdd(&hcnt[(u32)d.w >> SHIFTC], 1u);
    }
  }
  __syncthreads();
  for (int t = tid; t < NCB; t += 256) {
    u32 c = hcnt[t];
    gbase[t] = c ? atomicAdd(&gcurc[t * GSTRIDE], c) : 0u;
    hcnt[t] = 0u;
  }
  __syncthreads();
  // pass 2: scatter
  #pragma unroll 4
  for (int it = 0; it < CHUNK_C / 1024; ++it) {
    int e = base + it * 1024 + tid * 4;
    if (e < N_EDGES) {
      int4 d = dst4[(base >> 2) + it * 256 + tid];
      int4 s = src4[(base >> 2) + it * 256 + tid];
      #pragma unroll
      for (int q = 0; q < 4; ++q) {
        u32 dd = (u32)((q == 0) ? d.x : (q == 1) ? d.y : (q == 2) ? d.z : d.w);
        u32 ss = (u32)((q == 0) ? s.x : (q == 1) ? s.y : (q == 2) ? s.z : s.w);
        u32 cb = dd >> SHIFTC;
        u32 ofs = atomicAdd(&hcnt[cb], 1u);
        u32 p = gbase[cb] + ofs;
        if (p < CAPC)     // statistically impossible; memory-safety only
          coarse[(size_t)cb * CAPC + p] = ((dd & (NBINS - 1u)) << 17) | ss;
      }
    }
  }
}

// Fused front: blocks [0,NBLK_C) bucket edges, [NBLK_C,+NBLK_N) run gemm1.
// 489 blocks x 256 thr = 125K threads < 524K slots -> all co-resident.
__global__ __launch_bounds__(256) void k_front(
    const int* __restrict__ src, const int* __restrict__ dst,
    u32* __restrict__ gcurc, u32* __restrict__ coarse,
    const float* __restrict__ x, const float* __restrict__ W,
    float* __restrict__ p1, u16* __restrict__ q1b)
{
  if (blockIdx.x < NBLK_C)
    coarse_body(blockIdx.x, threadIdx.x, src, dst, gcurc, coarse);
  else
    gemm_body(blockIdx.x - NBLK_C, threadIdx.x, x, W, p1, q1b);
}

// Segment gather: assumes srt (LDS sorted src), st, en, l in scope.
// Produces s[DIM] = 8-lane-reduced partial sums.
#define SEG_GATHER(QSRC)                                                      \
  float s[DIM];                                                               \
  _Pragma("unroll")                                                           \
  for (int j = 0; j < DIM; ++j) s[j] = 0.f;                                   \
  {                                                                           \
    int k = st + l;                                                           \
    for (; k + 8 < en; k += 16) {                                             \
      int s0 = (int)srt[k], s1 = (int)srt[k + 8];                             \
      const u32* __restrict__ q0 = (const u32*)(QSRC + (size_t)s0 * QB);      \
      const u32* __restrict__ q1 = (const u32*)(QSRC + (size_t)s1 * QB);      \
      uint4 A0 = *(const uint4*)q0; u32 B0 = q0[4];                           \
      uint4 A1 = *(const uint4*)q1; u32 B1 = q1[4];                           \
      s[0] += bl(A0.x) + bl(A1.x); s[1] += bh(A0.x) + bh(A1.x);               \
      s[2] += bl(A0.y) + bl(A1.y); s[3] += bh(A0.y) + bh(A1.y);               \
      s[4] += bl(A0.z) + bl(A1.z); s[5] += bh(A0.z) + bh(A1.z);               \
      s[6] += bl(A0.w) + bl(A1.w); s[7] += bh(A0.w) + bh(A1.w);               \
      s[8] += bl(B0) + bl(B1);     s[9] += bh(B0) + bh(B1);                   \
    }                                                                         \
    if (k < en) {                                                             \
      int s0 = (int)srt[k];                                                   \
      const u32* __restrict__ q0 = (const u32*)(QSRC + (size_t)s0 * QB);      \
      uint4 A0 = *(const uint4*)q0; u32 B0 = q0[4];                           \
      s[0] += bl(A0.x); s[1] += bh(A0.x);                                     \
      s[2] += bl(A0.y); s[3] += bh(A0.y);                                     \
      s[4] += bl(A0.z); s[5] += bh(A0.z);                                     \
      s[6] += bl(A0.w); s[7] += bh(A0.w);                                     \
      s[8] += bl(B0);   s[9] += bh(B0);                                       \
    }                                                                         \
  }                                                                           \
  _Pragma("unroll")                                                           \
  for (int m = 1; m < 8; m <<= 1) {                                           \
    _Pragma("unroll")                                                         \
    for (int j = 0; j < DIM; ++j) s[j] += __shfl_xor(s[j], m, 8);             \
  }

// Layer 1: counting-sort a whole 128-dst bucket (~4092 records) in LDS,
// PERSIST the sorted order (coarse in place + segment table) for k_lay2,
// gather, epilogue h = relu(p1+mean), (p2,q2) = h @ W2.
__global__ __launch_bounds__(512) void k_lay1(
    const u32* __restrict__ gcurc, u32* __restrict__ coarse,
    const float* __restrict__ p1, const u16* __restrict__ q1b,
    const float* __restrict__ W2,
    float* __restrict__ p2, u16* __restrict__ q2b,
    u32* __restrict__ segg)
{
  __shared__ u32 lrec[CAPC];          // 18 KB
  __shared__ u32 srt[CAPC];           // 18 KB
  __shared__ u32 hist[NBINS];
  __shared__ u32 segst[NBINS + 1];
  __shared__ u32 rank[NBINS];
  __shared__ u32 wtot[2];
  __shared__ float w[2 * DIM * DIM];
  int tid = threadIdx.x;
  int c = blockIdx.x;
  for (int t = tid; t < 2 * DIM * DIM; t += 512) w[t] = W2[t];
  if (tid < NBINS) { hist[tid] = 0u; rank[tid] = 0u; }
  __syncthreads();
  int n = min((int)gcurc[c * GSTRIDE], CAPC);
  const u32* __restrict__ rc = coarse + (size_t)c * CAPC;
  for (int r = tid; r < n; r += 512) {
    u32 v = rc[r];
    lrec[r] = v;
    atomicAdd(&hist[(v >> 17) & (NBINS - 1u)], 1u);
  }
  __syncthreads();
  // 128-bin exclusive scan: intra-wave shfl scan + cross-wave offset
  if (tid < NBINS) {
    u32 h = hist[tid];
    u32 v = h;
    #pragma unroll
    for (int off = 1; off < 64; off <<= 1) {
      u32 t = __shfl_up(v, off, 64);
      if ((tid & 63) >= off) v += t;
    }
    if ((tid & 63) == 63) wtot[tid >> 6] = v;
    segst[tid] = v - h;
  }
  __syncthreads();
  if (tid >= 64 && tid < NBINS) segst[tid] += wtot[0];
  if (tid == 0) segst[NBINS] = wtot[0] + wtot[1];
  __syncthreads();
  for (int r = tid; r < n; r += 512) {
    u32 v = lrec[r];
    u32 dl = (v >> 17) & (NBINS - 1u);
    u32 pos = segst[dl] + atomicAdd(&rank[dl], 1u);
    srt[pos] = v & 0x1FFFFu;
  }
  __syncthreads();
  // persist sorted order (k_lay2 skips the whole sort)
  for (int r = tid; r < n; r += 512) coarse[(size_t)c * CAPC + r] = srt[r];
  if (tid <= NBINS) segg[(size_t)c * SEGW + tid] = segst[tid];
  // gather + epilogue: 64 groups of 8 lanes, 2 rounds cover 128 nodes
  int g0 = tid >> 3, l = tid & 7;
  #pragma unroll
  for (int rd = 0; rd < 2; ++rd) {
    int g2 = rd * 64 + g0;
    int st = (int)segst[g2], en = (int)segst[g2 + 1];
    SEG_GATHER(q1b)
    if (l == 0) {
      int i = c * NBINS + g2;
      if (i < N_NODES) {
        float inv = 1.0f / fmaxf((float)(en - st), 1.0f);
        const float* __restrict__ pr = p1 + (size_t)i * DIM;
        float h[DIM];
        #pragma unroll
        for (int j = 0; j < DIM; ++j) h[j] = fmaxf(pr[j] + s[j] * inv, 0.0f);
        float aa[DIM], bb[DIM];
        #pragma unroll
        for (int j = 0; j < DIM; ++j) {
          float t0 = 0.f, t1 = 0.f;
          #pragma unroll
          for (int kk = 0; kk < DIM; ++kk) {
            t0 += h[kk] * w[kk * DIM + j];
            t1 += h[kk] * w[(DIM + kk) * DIM + j];
          }
          aa[j] = t0; bb[j] = t1;
        }
        float* po = p2 + (size_t)i * DIM;
        #pragma unroll
        for (int j = 0; j < DIM; ++j) po[j] = aa[j];
        u32* qo = (u32*)(q2b + (size_t)i * QB);
        uint4 v0; u32 v1;
        v0.x = (u32)f2b(bb[0]) | ((u32)f2b(bb[1]) << 16);
        v0.y = (u32)f2b(bb[2]) | ((u32)f2b(bb[3]) << 16);
        v0.z = (u32)f2b(bb[4]) | ((u32)f2b(bb[5]) << 16);
        v0.w = (u32)f2b(bb[6]) | ((u32)f2b(bb[7]) << 16);
        v1   = (u32)f2b(bb[8]) | ((u32)f2b(bb[9]) << 16);
        *(uint4*)qo = v0;
        qo[4] = v1;
      }
    }
  }
}

// Layer 2: NO sort — stage the already-sorted records + segment table,
// gather, epilogue h2 = p2 + mean (f32, stride 12).
__global__ __launch_bounds__(512) void k_lay2(
    const u32* __restrict__ gcurc, const u32* __restrict__ coarse,
    const u32* __restrict__ segg,
    const float* __restrict__ p2, const u16* __restrict__ q2b,
    float* __restrict__ h2)
{
  __shared__ u32 srt[CAPC];           // 18 KB
  __shared__ u32 segst[NBINS + 1];
  int tid = threadIdx.x;
  int c = blockIdx.x;
  if (tid <= NBINS) segst[tid] = segg[(size_t)c * SEGW + tid];
  int n = min((int)gcurc[c * GSTRIDE], CAPC);
  const u32* __restrict__ rc = coarse + (size_t)c * CAPC;
  for (int r = tid; r < n; r += 512) srt[r] = rc[r];
  __syncthreads();
  int g0 = tid >> 3, l = tid & 7;
  #pragma unroll
  for (int rd = 0; rd < 2; ++rd) {
    int g2 = rd * 64 + g0;
    int st = (int)segst[g2], en = (int)segst[g2 + 1];
    SEG_GATHER(q2b)
    if (l == 0) {
      int i = c * NBINS + g2;
      if (i < N_NODES) {
        float inv = 1.0f / fmaxf((float)(en - st), 1.0f);
        const float* __restrict__ pr = p2 + (size_t)i * DIM;
        float* ho = h2 + (size_t)i * HPAD;
        #pragma unroll
        for (int j = 0; j < DIM; ++j) ho[j] = pr[j] + s[j] * inv;
      }
    }
  }
}

// one wave per graph: binary-search node range in sorted batch, mean-pool,
// dot with Wfc, sigmoid -> out[b]. Zero atomics.
__global__ __launch_bounds__(64) void k_pool(
    const float* __restrict__ h2, const int* __restrict__ batch,
    const float* __restrict__ Wfc, float* __restrict__ out)
{
  int b = blockIdx.x;
  int lo = 0, hi = N_NODES;
  while (lo < hi) { int m = (lo + hi) >> 1; if (batch[m] < b) lo = m + 1; else hi = m; }
  int start = lo;
  hi = N_NODES;
  while (lo < hi) { int m = (lo + hi) >> 1; if (batch[m] < b + 1) lo = m + 1; else hi = m; }
  int end = lo;
  float sum[DIM];
  #pragma unroll
  for (int j = 0; j < DIM; ++j) sum[j] = 0.f;
  for (int r = start + (int)threadIdx.x; r < end; r += 64) {
    const float4* __restrict__ p = (const float4*)(h2 + (size_t)r * HPAD);
    float4 r0 = p[0], r1 = p[1];
    float2 r2 = *(const float2*)(h2 + (size_t)r * HPAD + 8);
    sum[0] += r0.x; sum[1] += r0.y; sum[2] += r0.z; sum[3] += r0.w;
    sum[4] += r1.x; sum[5] += r1.y; sum[6] += r1.z; sum[7] += r1.w;
    sum[8] += r2.x; sum[9] += r2.y;
  }
  #pragma unroll
  for (int m = 1; m < 64; m <<= 1) {
    #pragma unroll
    for (int j = 0; j < DIM; ++j) sum[j] += __shfl_xor(sum[j], m, 64);
  }
  if (threadIdx.x == 0) {
    float inv = 1.0f / fmaxf((float)(end - start), 1.0f);
    float acc = 0.f;
    #pragma unroll
    for (int j = 0; j < DIM; ++j) acc += sum[j] * inv * Wfc[j];
    out[b] = 1.0f / (1.0f + expf(-acc));
  }
}

extern "C" void kernel_launch(void* const* d_in, const int* in_sizes, int n_in,
                              void* d_out, int out_size, void* d_ws, size_t ws_size,
                              hipStream_t stream)
{
  const float* x     = (const float*)d_in[0];
  const int*   ei    = (const int*)d_in[1];
  const int*   batch = (const int*)d_in[2];
  const float* W1    = (const float*)d_in[3];
  const float* W2    = (const float*)d_in[4];
  const float* Wfc   = (const float*)d_in[5];
  float* out = (float*)d_out;

  const int* src = ei;            // edge_index[0]
  const int* dst = ei + N_EDGES;  // edge_index[1]

  // ---- workspace layout (u32 element offsets), total ~34.1 MB ----
  u32* wsp = (u32*)d_ws;
  u32* gcurc  = wsp;                                  // 12,512 used (pad 12,544)
  u32* coarse = wsp + 12544;                          // 782*4608 = 3,603,456
  u32* segg   = coarse + (size_t)NCB * CAPC;          // 782*129 (pad 100,928)
  u32* after  = segg + 100928;
  u16*   q1b = (u16*)after;                           // 800,000 u32
  float* p1  = (float*)(after + 800000);              // 1,000,000 u32
  u16*   q2b = (u16*)(after + 1800000);               // 800,000 u32
  float* p2  = (float*)(after + 2600000);             // 1,000,000 u32
  float* h2  = (float*)(after + 3600000);             // 1,200,000 u32

  hipMemsetAsync(gcurc, 0, (size_t)NCB * GSTRIDE * sizeof(u32), stream);

  k_front<<<NBLK_C + NBLK_N, 256, 0, stream>>>(src, dst, gcurc, coarse,
                                               x, W1, p1, q1b);
  k_lay1<<<NCB, 512, 0, stream>>>(gcurc, coarse, p1, q1b, W2, p2, q2b, segg);
  k_lay2<<<NCB, 512, 0, stream>>>(gcurc, coarse, segg, p2, q2b, h2);
  k_pool<<<B_GRAPHS, 64, 0, stream>>>(h2, batch, Wfc, out);
}

// Round 4
// 227.519 us; speedup vs baseline: 1.0744x; 1.0744x over previous
//
#include <hip/hip_runtime.h>
#include <cstdint>

typedef unsigned int u32;
typedef unsigned short u16;

#define N_NODES 100000
#define N_EDGES 3200000
#define F_IN 128
#define DIM 10
#define QB 16            // bf16 elems per padded q row -> 32B
#define HPAD 12          // f32 h2 row stride (48B) for the pool kernel
#define B_GRAPHS 1000
#define NBLK_N 391       // ceil(N/256) gemm blocks

// Single-level bucketing: 782 buckets of 128 dst nodes each (dst>>7).
// CHUNK_C=8192 (391 blocks, parallelism of r2) + in-LDS counting sort so
// global writes are per-bucket contiguous RUNS (coalescing of r3's long
// segments). r2: direct scatter -> 77MB RMW writes. r3: 98 blocks -> 8%
// occupancy, latency-bound. This combines both fixes.
#define SHIFTC 7
#define NBINS 128        // dst & 127 within a bucket
#define NCB 782          // ceil(N/128)
#define CAPC 4608        // slots/bucket: mean 4092 + 8 sigma
#define CHUNK_C 8192     // edges per bucketing block
#define NBLK_C 391       // ceil(E/CHUNK_C)
#define GSTRIDE 16       // cursor padding: one 64B line per cursor
#define SEGW 129         // segment-start words per bucket (NBINS+1)

__device__ __forceinline__ u16 f2b(float f) {           // f32 -> bf16 (RNE)
  union { float f; u32 i; } c; c.f = f;
  u32 r = c.i + 0x7FFFu + ((c.i >> 16) & 1u);
  return (u16)(r >> 16);
}
__device__ __forceinline__ float bl(u32 u) {            // low bf16 -> f32
  union { u32 i; float f; } c; c.i = u << 16; return c.f;
}
__device__ __forceinline__ float bh(u32 u) {            // high bf16 -> f32
  union { u32 i; float f; } c; c.i = u & 0xFFFF0000u; return c.f;
}

// ---- gemm1 body: 1 thread/node, wave-uniform W indexing (s_loads) ----
__device__ __forceinline__ void gemm_body(
    int bid, int tid,
    const float* __restrict__ x, const float* __restrict__ W,
    float* __restrict__ p1, u16* __restrict__ q1b)
{
  int i = bid * 256 + tid;
  if (i >= N_NODES) return;
  const float4* __restrict__ xr = (const float4*)(x + (size_t)i * F_IN);
  float ap[DIM], aq[DIM];
  #pragma unroll
  for (int j = 0; j < DIM; ++j) { ap[j] = 0.f; aq[j] = 0.f; }
  #pragma unroll 4
  for (int k4 = 0; k4 < F_IN / 4; ++k4) {
    float4 v = xr[k4];
    const float* __restrict__ w0 = W + (k4 * 4) * DIM;
    const float* __restrict__ w1 = W + (F_IN + k4 * 4) * DIM;
    #pragma unroll
    for (int j = 0; j < DIM; ++j) {
      ap[j] += v.x * w0[j] + v.y * w0[DIM + j] + v.z * w0[2 * DIM + j] + v.w * w0[3 * DIM + j];
      aq[j] += v.x * w1[j] + v.y * w1[DIM + j] + v.z * w1[2 * DIM + j] + v.w * w1[3 * DIM + j];
    }
  }
  float* pr = p1 + (size_t)i * DIM;
  #pragma unroll
  for (int j = 0; j < DIM; ++j) pr[j] = ap[j];
  u32* qr = (u32*)(q1b + (size_t)i * QB);
  uint4 v0; u32 v1;
  v0.x = (u32)f2b(aq[0]) | ((u32)f2b(aq[1]) << 16);
  v0.y = (u32)f2b(aq[2]) | ((u32)f2b(aq[3]) << 16);
  v0.z = (u32)f2b(aq[4]) | ((u32)f2b(aq[5]) << 16);
  v0.w = (u32)f2b(aq[6]) | ((u32)f2b(aq[7]) << 16);
  v1   = (u32)f2b(aq[8]) | ((u32)f2b(aq[9]) << 16);
  *(uint4*)qr = v0;
  qr[4] = v1;
}

// ---- bucketing body: partition edges into 782 ranges (128 dst each) ----
// Record: ((dst & 127) << 17) | src   (src < 2^17)
// In-LDS counting sort by bucket id, then coalesced run-copy to global.
__device__ __forceinline__ void coarse_body(
    int bid, int tid,
    const int* __restrict__ src, const int* __restrict__ dst,
    u32* __restrict__ gcurc, u32* __restrict__ coarse)
{
  __shared__ u32 srt[CHUNK_C];        // 32 KB: chunk sorted by bucket id
  __shared__ u32 segst[NCB + 1];      // 3.1 KB: local exclusive scan
  __shared__ u32 rank[NCB];           // 3.1 KB: hist, then scatter rank
  __shared__ u32 gbase[NCB];          // 3.1 KB: global base per bucket
  __shared__ u32 wtot[4];

  for (int t = tid; t < NCB; t += 256) rank[t] = 0u;
  __syncthreads();

  int base = bid * CHUNK_C;
  const int4* __restrict__ dst4 = (const int4*)dst;
  const int4* __restrict__ src4 = (const int4*)src;
  // pass 1: histogram (int4 loads: 4 edges/thread/iter, 4 indep atomics)
  #pragma unroll
  for (int it = 0; it < CHUNK_C / 1024; ++it) {
    int e = base + it * 1024 + tid * 4;
    if (e < N_EDGES) {     // N_EDGES % 4 == 0, e % 4 == 0 -> whole int4 ok
      int4 d = dst4[(base >> 2) + it * 256 + tid];
      atomicAdd(&rank[(u32)d.x >> SHIFTC], 1u);
      atomicAdd(&rank[(u32)d.y >> SHIFTC], 1u);
      atomicAdd(&rank[(u32)d.z >> SHIFTC], 1u);
      atomicAdd(&rank[(u32)d.w >> SHIFTC], 1u);
    }
  }
  __syncthreads();

  // exclusive scan of 782 bins: 4 bins/thread (threads 0..195) + wave scan
  u32 lh[4] = {0u, 0u, 0u, 0u};
  u32 lsum = 0u;
  if (tid < 196) {
    #pragma unroll
    for (int k = 0; k < 4; ++k) {
      int b4 = tid * 4 + k;
      lh[k] = (b4 < NCB) ? rank[b4] : 0u;
      lsum += lh[k];
    }
  }
  u32 v = lsum;
  #pragma unroll
  for (int off = 1; off < 64; off <<= 1) {
    u32 t = __shfl_up(v, off, 64);
    if ((tid & 63) >= off) v += t;
  }
  if ((tid & 63) == 63) wtot[tid >> 6] = v;
  __syncthreads();
  u32 wofs = 0u;
  #pragma unroll
  for (int w = 0; w < 3; ++w) if ((tid >> 6) > w) wofs += wtot[w];
  if (tid < 196) {
    u32 excl = wofs + v - lsum;      // exclusive prefix across threads
    #pragma unroll
    for (int k = 0; k < 4; ++k) {
      int b4 = tid * 4 + k;
      if (b4 < NCB) segst[b4] = excl;
      excl += lh[k];
    }
    if (tid == 195) segst[NCB] = excl;     // chunk total
  }
  __syncthreads();

  // reserve global space per bucket; reset rank for the scatter pass
  for (int t = tid; t < NCB; t += 256) {
    u32 c = segst[t + 1] - segst[t];
    gbase[t] = c ? atomicAdd(&gcurc[t * GSTRIDE], c) : 0u;
    rank[t] = 0u;
  }
  __syncthreads();

  // pass 2: scatter into LDS (sorted by bucket id)
  #pragma unroll
  for (int it = 0; it < CHUNK_C / 1024; ++it) {
    int e = base + it * 1024 + tid * 4;
    if (e < N_EDGES) {
      int4 d = dst4[(base >> 2) + it * 256 + tid];
      int4 s = src4[(base >> 2) + it * 256 + tid];
      #pragma unroll
      for (int q = 0; q < 4; ++q) {
        u32 dd = (u32)((q == 0) ? d.x : (q == 1) ? d.y : (q == 2) ? d.z : d.w);
        u32 ss = (u32)((q == 0) ? s.x : (q == 1) ? s.y : (q == 2) ? s.z : s.w);
        u32 cb = dd >> SHIFTC;
        u32 pos = segst[cb] + atomicAdd(&rank[cb], 1u);
        srt[pos] = ((dd & (NBINS - 1u)) << 17) | ss;   // pos < CHUNK_C always
      }
    }
  }
  __syncthreads();

  // phase W: 16-lane groups copy per-bucket runs (contiguous -> coalesced)
  int grp = tid >> 4, lane = tid & 15;
  for (int cb = grp; cb < NCB; cb += 16) {
    u32 st = segst[cb];
    u32 cnt = segst[cb + 1] - st;
    u32 gb = gbase[cb];
    for (u32 r = lane; r < cnt; r += 16u) {
      u32 p = gb + r;
      if (p < CAPC)     // statistically impossible; memory-safety only
        coarse[(size_t)cb * CAPC + p] = srt[st + r];
    }
  }
}

// Fused front: blocks [0,NBLK_C) bucket edges, [NBLK_C,+NBLK_N) run gemm1.
// 782 blocks; LDS 42KB -> 3 blocks/CU -> ~all co-resident, 12 waves/CU.
__global__ __launch_bounds__(256) void k_front(
    const int* __restrict__ src, const int* __restrict__ dst,
    u32* __restrict__ gcurc, u32* __restrict__ coarse,
    const float* __restrict__ x, const float* __restrict__ W,
    float* __restrict__ p1, u16* __restrict__ q1b)
{
  if (blockIdx.x < NBLK_C)
    coarse_body(blockIdx.x, threadIdx.x, src, dst, gcurc, coarse);
  else
    gemm_body(blockIdx.x - NBLK_C, threadIdx.x, x, W, p1, q1b);
}

// Segment gather: assumes srt (LDS sorted src), st, en, l in scope.
// Produces s[DIM] = 8-lane-reduced partial sums.
#define SEG_GATHER(QSRC)                                                      \
  float s[DIM];                                                               \
  _Pragma("unroll")                                                           \
  for (int j = 0; j < DIM; ++j) s[j] = 0.f;                                   \
  {                                                                           \
    int k = st + l;                                                           \
    for (; k + 8 < en; k += 16) {                                             \
      int s0 = (int)srt[k], s1 = (int)srt[k + 8];                             \
      const u32* __restrict__ q0 = (const u32*)(QSRC + (size_t)s0 * QB);      \
      const u32* __restrict__ q1 = (const u32*)(QSRC + (size_t)s1 * QB);      \
      uint4 A0 = *(const uint4*)q0; u32 B0 = q0[4];                           \
      uint4 A1 = *(const uint4*)q1; u32 B1 = q1[4];                           \
      s[0] += bl(A0.x) + bl(A1.x); s[1] += bh(A0.x) + bh(A1.x);               \
      s[2] += bl(A0.y) + bl(A1.y); s[3] += bh(A0.y) + bh(A1.y);               \
      s[4] += bl(A0.z) + bl(A1.z); s[5] += bh(A0.z) + bh(A1.z);               \
      s[6] += bl(A0.w) + bl(A1.w); s[7] += bh(A0.w) + bh(A1.w);               \
      s[8] += bl(B0) + bl(B1);     s[9] += bh(B0) + bh(B1);                   \
    }                                                                         \
    if (k < en) {                                                             \
      int s0 = (int)srt[k];                                                   \
      const u32* __restrict__ q0 = (const u32*)(QSRC + (size_t)s0 * QB);      \
      uint4 A0 = *(const uint4*)q0; u32 B0 = q0[4];                           \
      s[0] += bl(A0.x); s[1] += bh(A0.x);                                     \
      s[2] += bl(A0.y); s[3] += bh(A0.y);                                     \
      s[4] += bl(A0.z); s[5] += bh(A0.z);                                     \
      s[6] += bl(A0.w); s[7] += bh(A0.w);                                     \
      s[8] += bl(B0);   s[9] += bh(B0);                                       \
    }                                                                         \
  }                                                                           \
  _Pragma("unroll")                                                           \
  for (int m = 1; m < 8; m <<= 1) {                                           \
    _Pragma("unroll")                                                         \
    for (int j = 0; j < DIM; ++j) s[j] += __shfl_xor(s[j], m, 8);             \
  }

// Layer 1: counting-sort a whole 128-dst bucket (~4092 records) in LDS,
// PERSIST the sorted order (coarse in place + segment table) for k_lay2,
// gather, epilogue h = relu(p1+mean), (p2,q2) = h @ W2.
__global__ __launch_bounds__(512) void k_lay1(
    const u32* __restrict__ gcurc, u32* __restrict__ coarse,
    const float* __restrict__ p1, const u16* __restrict__ q1b,
    const float* __restrict__ W2,
    float* __restrict__ p2, u16* __restrict__ q2b,
    u32* __restrict__ segg)
{
  __shared__ u32 lrec[CAPC];          // 18 KB
  __shared__ u32 srt[CAPC];           // 18 KB
  __shared__ u32 hist[NBINS];
  __shared__ u32 segst[NBINS + 1];
  __shared__ u32 rank[NBINS];
  __shared__ u32 wtot[2];
  __shared__ float w[2 * DIM * DIM];
  int tid = threadIdx.x;
  int c = blockIdx.x;
  for (int t = tid; t < 2 * DIM * DIM; t += 512) w[t] = W2[t];
  if (tid < NBINS) { hist[tid] = 0u; rank[tid] = 0u; }
  __syncthreads();
  int n = min((int)gcurc[c * GSTRIDE], CAPC);
  const u32* __restrict__ rc = coarse + (size_t)c * CAPC;
  for (int r = tid; r < n; r += 512) {
    u32 v = rc[r];
    lrec[r] = v;
    atomicAdd(&hist[(v >> 17) & (NBINS - 1u)], 1u);
  }
  __syncthreads();
  // 128-bin exclusive scan: intra-wave shfl scan + cross-wave offset
  if (tid < NBINS) {
    u32 h = hist[tid];
    u32 v = h;
    #pragma unroll
    for (int off = 1; off < 64; off <<= 1) {
      u32 t = __shfl_up(v, off, 64);
      if ((tid & 63) >= off) v += t;
    }
    if ((tid & 63) == 63) wtot[tid >> 6] = v;
    segst[tid] = v - h;
  }
  __syncthreads();
  if (tid >= 64 && tid < NBINS) segst[tid] += wtot[0];
  if (tid == 0) segst[NBINS] = wtot[0] + wtot[1];
  __syncthreads();
  for (int r = tid; r < n; r += 512) {
    u32 v = lrec[r];
    u32 dl = (v >> 17) & (NBINS - 1u);
    u32 pos = segst[dl] + atomicAdd(&rank[dl], 1u);
    srt[pos] = v & 0x1FFFFu;
  }
  __syncthreads();
  // persist sorted order (k_lay2 skips the whole sort)
  for (int r = tid; r < n; r += 512) coarse[(size_t)c * CAPC + r] = srt[r];
  if (tid <= NBINS) segg[(size_t)c * SEGW + tid] = segst[tid];
  // gather + epilogue: 64 groups of 8 lanes, 2 rounds cover 128 nodes
  int g0 = tid >> 3, l = tid & 7;
  #pragma unroll
  for (int rd = 0; rd < 2; ++rd) {
    int g2 = rd * 64 + g0;
    int st = (int)segst[g2], en = (int)segst[g2 + 1];
    SEG_GATHER(q1b)
    if (l == 0) {
      int i = c * NBINS + g2;
      if (i < N_NODES) {
        float inv = 1.0f / fmaxf((float)(en - st), 1.0f);
        const float* __restrict__ pr = p1 + (size_t)i * DIM;
        float h[DIM];
        #pragma unroll
        for (int j = 0; j < DIM; ++j) h[j] = fmaxf(pr[j] + s[j] * inv, 0.0f);
        float aa[DIM], bb[DIM];
        #pragma unroll
        for (int j = 0; j < DIM; ++j) {
          float t0 = 0.f, t1 = 0.f;
          #pragma unroll
          for (int kk = 0; kk < DIM; ++kk) {
            t0 += h[kk] * w[kk * DIM + j];
            t1 += h[kk] * w[(DIM + kk) * DIM + j];
          }
          aa[j] = t0; bb[j] = t1;
        }
        float* po = p2 + (size_t)i * DIM;
        #pragma unroll
        for (int j = 0; j < DIM; ++j) po[j] = aa[j];
        u32* qo = (u32*)(q2b + (size_t)i * QB);
        uint4 v0; u32 v1;
        v0.x = (u32)f2b(bb[0]) | ((u32)f2b(bb[1]) << 16);
        v0.y = (u32)f2b(bb[2]) | ((u32)f2b(bb[3]) << 16);
        v0.z = (u32)f2b(bb[4]) | ((u32)f2b(bb[5]) << 16);
        v0.w = (u32)f2b(bb[6]) | ((u32)f2b(bb[7]) << 16);
        v1   = (u32)f2b(bb[8]) | ((u32)f2b(bb[9]) << 16);
        *(uint4*)qo = v0;
        qo[4] = v1;
      }
    }
  }
}

// Layer 2: NO sort — stage the already-sorted records + segment table,
// gather, epilogue h2 = p2 + mean (f32, stride 12).
__global__ __launch_bounds__(512) void k_lay2(
    const u32* __restrict__ gcurc, const u32* __restrict__ coarse,
    const u32* __restrict__ segg,
    const float* __restrict__ p2, const u16* __restrict__ q2b,
    float* __restrict__ h2)
{
  __shared__ u32 srt[CAPC];           // 18 KB
  __shared__ u32 segst[NBINS + 1];
  int tid = threadIdx.x;
  int c = blockIdx.x;
  if (tid <= NBINS) segst[tid] = segg[(size_t)c * SEGW + tid];
  int n = min((int)gcurc[c * GSTRIDE], CAPC);
  const u32* __restrict__ rc = coarse + (size_t)c * CAPC;
  for (int r = tid; r < n; r += 512) srt[r] = rc[r];
  __syncthreads();
  int g0 = tid >> 3, l = tid & 7;
  #pragma unroll
  for (int rd = 0; rd < 2; ++rd) {
    int g2 = rd * 64 + g0;
    int st = (int)segst[g2], en = (int)segst[g2 + 1];
    SEG_GATHER(q2b)
    if (l == 0) {
      int i = c * NBINS + g2;
      if (i < N_NODES) {
        float inv = 1.0f / fmaxf((float)(en - st), 1.0f);
        const float* __restrict__ pr = p2 + (size_t)i * DIM;
        float* ho = h2 + (size_t)i * HPAD;
        #pragma unroll
        for (int j = 0; j < DIM; ++j) ho[j] = pr[j] + s[j] * inv;
      }
    }
  }
}

// one wave per graph: binary-search node range in sorted batch, mean-pool,
// dot with Wfc, sigmoid -> out[b]. Zero atomics.
__global__ __launch_bounds__(64) void k_pool(
    const float* __restrict__ h2, const int* __restrict__ batch,
    const float* __restrict__ Wfc, float* __restrict__ out)
{
  int b = blockIdx.x;
  int lo = 0, hi = N_NODES;
  while (lo < hi) { int m = (lo + hi) >> 1; if (batch[m] < b) lo = m + 1; else hi = m; }
  int start = lo;
  hi = N_NODES;
  while (lo < hi) { int m = (lo + hi) >> 1; if (batch[m] < b + 1) lo = m + 1; else hi = m; }
  int end = lo;
  float sum[DIM];
  #pragma unroll
  for (int j = 0; j < DIM; ++j) sum[j] = 0.f;
  for (int r = start + (int)threadIdx.x; r < end; r += 64) {
    const float4* __restrict__ p = (const float4*)(h2 + (size_t)r * HPAD);
    float4 r0 = p[0], r1 = p[1];
    float2 r2 = *(const float2*)(h2 + (size_t)r * HPAD + 8);
    sum[0] += r0.x; sum[1] += r0.y; sum[2] += r0.z; sum[3] += r0.w;
    sum[4] += r1.x; sum[5] += r1.y; sum[6] += r1.z; sum[7] += r1.w;
    sum[8] += r2.x; sum[9] += r2.y;
  }
  #pragma unroll
  for (int m = 1; m < 64; m <<= 1) {
    #pragma unroll
    for (int j = 0; j < DIM; ++j) sum[j] += __shfl_xor(sum[j], m, 64);
  }
  if (threadIdx.x == 0) {
    float inv = 1.0f / fmaxf((float)(end - start), 1.0f);
    float acc = 0.f;
    #pragma unroll
    for (int j = 0; j < DIM; ++j) acc += sum[j] * inv * Wfc[j];
    out[b] = 1.0f / (1.0f + expf(-acc));
  }
}

extern "C" void kernel_launch(void* const* d_in, const int* in_sizes, int n_in,
                              void* d_out, int out_size, void* d_ws, size_t ws_size,
                              hipStream_t stream)
{
  const float* x     = (const float*)d_in[0];
  const int*   ei    = (const int*)d_in[1];
  const int*   batch = (const int*)d_in[2];
  const float* W1    = (const float*)d_in[3];
  const float* W2    = (const float*)d_in[4];
  const float* Wfc   = (const float*)d_in[5];
  float* out = (float*)d_out;

  const int* src = ei;            // edge_index[0]
  const int* dst = ei + N_EDGES;  // edge_index[1]

  // ---- workspace layout (u32 element offsets), total ~34.1 MB ----
  u32* wsp = (u32*)d_ws;
  u32* gcurc  = wsp;                                  // 12,512 used (pad 12,544)
  u32* coarse = wsp + 12544;                          // 782*4608 = 3,603,456
  u32* segg   = coarse + (size_t)NCB * CAPC;          // 782*129 (pad 100,928)
  u32* after  = segg + 100928;
  u16*   q1b = (u16*)after;                           // 800,000 u32
  float* p1  = (float*)(after + 800000);              // 1,000,000 u32
  u16*   q2b = (u16*)(after + 1800000);               // 800,000 u32
  float* p2  = (float*)(after + 2600000);             // 1,000,000 u32
  float* h2  = (float*)(after + 3600000);             // 1,200,000 u32

  hipMemsetAsync(gcurc, 0, (size_t)NCB * GSTRIDE * sizeof(u32), stream);

  k_front<<<NBLK_C + NBLK_N, 256, 0, stream>>>(src, dst, gcurc, coarse,
                                               x, W1, p1, q1b);
  k_lay1<<<NCB, 512, 0, stream>>>(gcurc, coarse, p1, q1b, W2, p2, q2b, segg);
  k_lay2<<<NCB, 512, 0, stream>>>(gcurc, coarse, segg, p2, q2b, h2);
  k_pool<<<B_GRAPHS, 64, 0, stream>>>(h2, batch, Wfc, out);
}